// Round 4
// baseline (283.129 us; speedup 1.0000x reference)
//
#include <hip/hip_runtime.h>

typedef _Float16 f16;
typedef _Float16 h8 __attribute__((ext_vector_type(8)));
typedef float f4 __attribute__((ext_vector_type(4)));

typedef const __attribute__((address_space(1))) char gchar;
typedef __attribute__((address_space(3))) char lchar;

#define B_ 4
#define S_ 2048
#define D_ 1024
#define H_ 1024

// ---------------- fused fp32 -> fp16 cast of all six inputs ----------------
#define NGX (8388608L / 8)
#define NGW (1048576L / 8)

__global__ __launch_bounds__(256) void cast_all(
    const float* __restrict__ x1, const float* __restrict__ x2, const float* __restrict__ x3,
    const float* __restrict__ wq, const float* __restrict__ wk, const float* __restrict__ wv,
    f16* __restrict__ o1, f16* __restrict__ o2, f16* __restrict__ o3,
    f16* __restrict__ o4, f16* __restrict__ o5, f16* __restrict__ o6) {
  const long NG = 3 * NGX + 3 * NGW;
  long g = blockIdx.x * 256L + threadIdx.x;
  const long stride = (long)gridDim.x * 256L;
  for (; g < NG; g += stride) {
    const float* in;
    f16* out;
    long off;
    if (g < 3 * NGX) {
      const long w = g >> 20;
      off = (g - w * NGX) * 8;
      in = w == 0 ? x1 : (w == 1 ? x2 : x3);
      out = w == 0 ? o1 : (w == 1 ? o2 : o3);
    } else {
      const long gg = g - 3 * NGX;
      const long h = gg >> 17;
      off = (gg - h * NGW) * 8;
      in = h == 0 ? wq : (h == 1 ? wk : wv);
      out = h == 0 ? o4 : (h == 1 ? o5 : o6);
    }
    float4 u = *(const float4*)(in + off);
    float4 v = *(const float4*)(in + off + 4);
    h8 o;
    o[0] = (f16)u.x; o[1] = (f16)u.y; o[2] = (f16)u.z; o[3] = (f16)u.w;
    o[4] = (f16)v.x; o[5] = (f16)v.y; o[6] = (f16)v.z; o[7] = (f16)v.w;
    *(h8*)(out + off) = o;
  }
}

// ---------------- 256x256 GEMM: C = A * B^T, counted-vmcnt pipeline ----------------
// A: [M,K] f16 row-major; B: [N,K] f16 row-major. Flat 1-D grid (must be %8==0),
// decomposed bx-fastest after bijective XCD swizzle. Per-batch strides sA/sB/sC.
// MODE 0: fp32 C[m*N+n]
// MODE 3: f16; bz<2 -> C[m*N+n]; bz==2 -> transposed V^T: C[2*sC + ((m>>11)*N+n)*2048 + (m&2047)]
#define BM 256
#define BKT 64
#define NT_CHUNKF16 512  // 1024B chunk = 512 f16

template <int MODE>
__global__ __launch_bounds__(512, 2) void gemm256(const f16* __restrict__ A,
                                                  const f16* __restrict__ Bm,
                                                  void* __restrict__ C,
                                                  int N, int K,
                                                  long sA, long sB, long sC,
                                                  int gx, int gy) {
  extern __shared__ __align__(16) f16 smem[];  // [buf][mat][256*64] = 128 KiB

  // bijective XCD swizzle (gridDim.x % 8 == 0)
  const int cpx = gridDim.x >> 3;
  const int flat = blockIdx.x;
  const int wgid = (flat & 7) * cpx + (flat >> 3);
  const int bx = wgid % gx;
  const int rem = wgid / gx;
  const int by = rem % gy;
  const int bz = rem / gy;

  A += (long)bz * sA;
  Bm += (long)bz * sB;
  const int m0 = bx * BM, n0 = by * BM;

  const int tid = threadIdx.x;
  const int lane = tid & 63;
  const int w = tid >> 6;           // 0..7
  const int wm = w >> 2, wn = w & 3;

  // stage mapping: chunk = 8 rows x 64 f16 (1024B); lane l -> row +(l>>3),
  // source slot pre-swizzled so linear LDS write == swizzled layout.
  const int srow = lane >> 3;
  const int sslot = (lane & 7) ^ srow;

  // fragment read params
  const int fr = lane & 15;
  const int kq = lane >> 4;         // 0..3

  f4 acc[8][4] = {};

  const int NT = K / BKT;

  auto STAGE = [&](int buf, int t) {
    const long k0 = (long)t * BKT;
#pragma unroll
    for (int j = 0; j < 4; ++j) {
      const int c = w * 4 + j;      // chunk 0..31 (8 rows each)
      __builtin_amdgcn_global_load_lds(
          (gchar*)(A + (long)(m0 + c * 8 + srow) * K + k0 + sslot * 8),
          (lchar*)&smem[(buf * 2 + 0) * 16384 + c * NT_CHUNKF16], 16, 0, 0);
      __builtin_amdgcn_global_load_lds(
          (gchar*)(Bm + (long)(n0 + c * 8 + srow) * K + k0 + sslot * 8),
          (lchar*)&smem[(buf * 2 + 1) * 16384 + c * NT_CHUNKF16], 16, 0, 0);
    }
  };

  // swizzled LDS fragment read: element (row r, k-slot s) lives at r*64 + (s^(r&7))*8
  auto RD = [&](const f16* base, int r, int kk) -> h8 {
    const int s = kk * 4 + kq;
    return *(const h8*)(base + r * 64 + ((s ^ (r & 7)) * 8));
  };

  STAGE(0, 0);
  STAGE(1, 1);

  int cur = 0;
  for (int t = 0; t < NT; ++t) {
    asm volatile("s_waitcnt vmcnt(8)" ::: "memory");  // this tile's 8 loads done; next tile's stay in flight
    __builtin_amdgcn_s_barrier();                     // all waves' loads for this tile landed
    __builtin_amdgcn_sched_barrier(0);

    const f16* la = &smem[(cur * 2 + 0) * 16384];
    const f16* lb = &smem[(cur * 2 + 1) * 16384];
#pragma unroll
    for (int kk = 0; kk < 2; ++kk) {
      h8 af[8], bf[4];
#pragma unroll
      for (int mi = 0; mi < 8; ++mi) af[mi] = RD(la, wm * 128 + mi * 16 + fr, kk);
#pragma unroll
      for (int ni = 0; ni < 4; ++ni) bf[ni] = RD(lb, wn * 64 + ni * 16 + fr, kk);
#pragma unroll
      for (int mi = 0; mi < 8; ++mi)
#pragma unroll
        for (int ni = 0; ni < 4; ++ni)
          acc[mi][ni] = __builtin_amdgcn_mfma_f32_16x16x32_f16(af[mi], bf[ni], acc[mi][ni], 0, 0, 0);
    }

    __builtin_amdgcn_sched_barrier(0);
    __builtin_amdgcn_s_barrier();   // all waves done reading buf[cur]
    int tn = t + 2;
    if (tn >= NT) tn = NT - 1;      // redundant tail re-stage keeps vmcnt counts uniform
    STAGE(cur, tn);
    cur ^= 1;
  }
  asm volatile("s_waitcnt vmcnt(0)" ::: "memory");  // drain DMA before LDS dealloc

  // epilogue: C/D layout: col = lane&15, row = (lane>>4)*4 + reg
  const int fq = (lane >> 4) * 4;
#pragma unroll
  for (int mi = 0; mi < 8; ++mi) {
#pragma unroll
    for (int ni = 0; ni < 4; ++ni) {
#pragma unroll
      for (int i = 0; i < 4; ++i) {
        const int row = m0 + wm * 128 + mi * 16 + fq + i;
        const int col = n0 + wn * 64 + ni * 16 + fr;
        const float val = acc[mi][ni][i];
        if constexpr (MODE == 0) {
          float* Cp = (float*)C + (long)bz * sC;
          Cp[(long)row * N + col] = val;
        } else {
          if (bz < 2) {
            f16* Cp = (f16*)C + (long)bz * sC;
            Cp[(long)row * N + col] = (f16)val;
          } else {
            f16* Cp = (f16*)C + 2 * sC;
            Cp[((long)(row >> 11) * N + col) * 2048 + (row & 2047)] = (f16)val;
          }
        }
      }
    }
  }
}

// ---------------- fused scale + mask + softmax, scores f32 -> P f16 ----------------
__global__ __launch_bounds__(256) void softmax_rows(const float* __restrict__ Sc,
                                                    const float* __restrict__ mask,
                                                    f16* __restrict__ P, float scale) {
  const long row = blockIdx.x;
  const float* s = Sc + row * (long)S_;
  const float* mk = mask + row * (long)S_;
  const int t = threadIdx.x;

  float4 a0 = *(const float4*)(s + t * 8);
  float4 a1 = *(const float4*)(s + t * 8 + 4);
  float4 b0 = *(const float4*)(mk + t * 8);
  float4 b1 = *(const float4*)(mk + t * 8 + 4);
  float v[8] = {a0.x * scale + b0.x, a0.y * scale + b0.y,
                a0.z * scale + b0.z, a0.w * scale + b0.w,
                a1.x * scale + b1.x, a1.y * scale + b1.y,
                a1.z * scale + b1.z, a1.w * scale + b1.w};

  float mx = v[0];
#pragma unroll
  for (int j = 1; j < 8; ++j) mx = fmaxf(mx, v[j]);
  for (int o = 32; o > 0; o >>= 1) mx = fmaxf(mx, __shfl_xor(mx, o));

  __shared__ float redm[4];
  __shared__ float reds[4];
  const int w = t >> 6;
  if ((t & 63) == 0) redm[w] = mx;
  __syncthreads();
  mx = fmaxf(fmaxf(redm[0], redm[1]), fmaxf(redm[2], redm[3]));

  float e[8];
  float sum = 0.f;
#pragma unroll
  for (int j = 0; j < 8; ++j) { e[j] = __expf(v[j] - mx); sum += e[j]; }
  for (int o = 32; o > 0; o >>= 1) sum += __shfl_xor(sum, o);
  if ((t & 63) == 0) reds[w] = sum;
  __syncthreads();
  sum = reds[0] + reds[1] + reds[2] + reds[3];
  const float inv = 1.0f / sum;

  h8 o;
#pragma unroll
  for (int j = 0; j < 8; ++j) o[j] = (f16)(e[j] * inv);
  *(h8*)(P + row * (long)S_ + t * 8) = o;
}

extern "C" void kernel_launch(void* const* d_in, const int* in_sizes, int n_in,
                              void* d_out, int out_size, void* d_ws, size_t ws_size,
                              hipStream_t stream) {
  const float* x1 = (const float*)d_in[0];
  const float* x2 = (const float*)d_in[1];
  const float* x3 = (const float*)d_in[2];
  const float* mask = (const float*)d_in[3];
  const float* Wq = (const float*)d_in[4];
  const float* Wk = (const float*)d_in[5];
  const float* Wv = (const float*)d_in[6];

  const long nx = (long)B_ * S_ * D_;
  const long nw = (long)H_ * D_;
  const long nqkv = (long)B_ * S_ * H_;
  const long nsc = (long)B_ * S_ * S_;

  char* ws = (char*)d_ws;
  f16* x1h = (f16*)ws; ws += nx * 2;
  f16* x2h = (f16*)ws; ws += nx * 2;   // contiguous after x1h
  f16* x3h = (f16*)ws; ws += nx * 2;
  f16* wqh = (f16*)ws; ws += nw * 2;
  f16* wkh = (f16*)ws; ws += nw * 2;   // contiguous after wqh
  f16* wvh = (f16*)ws; ws += nw * 2;
  f16* qh  = (f16*)ws; ws += nqkv * 2;
  f16* kh  = (f16*)ws; ws += nqkv * 2; // contiguous after qh
  f16* vth = (f16*)ws; ws += nqkv * 2; // [b][h][s]
  float* sc = (float*)ws; ws += nsc * 4;
  f16* ph  = (f16*)ws; ws += nsc * 2;

  static_assert(sizeof(f16) == 2, "");
  const size_t SMEM = 131072;  // 128 KiB dynamic LDS
  hipFuncSetAttribute((const void*)gemm256<3>, hipFuncAttributeMaxDynamicSharedMemorySize, (int)SMEM);
  hipFuncSetAttribute((const void*)gemm256<0>, hipFuncAttributeMaxDynamicSharedMemorySize, (int)SMEM);

  cast_all<<<2048, 256, 0, stream>>>(x1, x2, x3, Wq, Wk, Wv,
                                     x1h, x2h, x3h, wqh, wkh, wvh);

  const dim3 blk(512);
  // QKV projections, batched z=3: A_b = x_b [8192x1024], B_b = W_b, C_b (V transposed)
  // grid 32*4*3 = 384 blocks
  gemm256<3><<<dim3(384), blk, SMEM, stream>>>(x1h, wqh, qh, 1024, 1024,
                                               nx, nw, nqkv, 32, 4);
  // scores[b] = Q[b] K[b]^T : 2048x2048x1024 x4, fp32; grid 8*8*4 = 256
  gemm256<0><<<dim3(256), blk, SMEM, stream>>>(qh, kh, sc, 2048, 1024,
                                               (long)S_ * H_, (long)S_ * H_, (long)S_ * S_, 8, 8);
  // P = softmax(scores * 1/sqrt(H) + mask)
  softmax_rows<<<B_ * S_, 256, 0, stream>>>(sc, mask, ph, 0.03125f);
  // out[b] = P[b] (V^T[b])^T : 2048x1024x2048 x4, fp32 to d_out; grid 8*4*4 = 128
  gemm256<0><<<dim3(128), blk, SMEM, stream>>>(ph, vth, d_out, 1024, 2048,
                                               (long)S_ * S_, (long)S_ * H_, (long)S_ * H_, 8, 4);
}

// Round 5
// 253.849 us; speedup vs baseline: 1.1153x; 1.1153x over previous
//
#include <hip/hip_runtime.h>

typedef _Float16 f16;
typedef _Float16 h8 __attribute__((ext_vector_type(8)));
typedef float f4 __attribute__((ext_vector_type(4)));

typedef const __attribute__((address_space(1))) char gchar;
typedef __attribute__((address_space(3))) char lchar;

#define B_ 4
#define S_ 2048
#define D_ 1024
#define H_ 1024

template <int N>
__device__ __forceinline__ void vmwait() {
  if constexpr (N == 0) asm volatile("s_waitcnt vmcnt(0)" ::: "memory");
  else if constexpr (N == 6) asm volatile("s_waitcnt vmcnt(6)" ::: "memory");
  else if constexpr (N == 8) asm volatile("s_waitcnt vmcnt(8)" ::: "memory");
}

// ---------------- fused fp32 -> fp16 cast of all six inputs ----------------
#define NGX (8388608L / 8)
#define NGW (1048576L / 8)

__global__ __launch_bounds__(256) void cast_all(
    const float* __restrict__ x1, const float* __restrict__ x2, const float* __restrict__ x3,
    const float* __restrict__ wq, const float* __restrict__ wk, const float* __restrict__ wv,
    f16* __restrict__ o1, f16* __restrict__ o2, f16* __restrict__ o3,
    f16* __restrict__ o4, f16* __restrict__ o5, f16* __restrict__ o6) {
  const long NG = 3 * NGX + 3 * NGW;
  long g = blockIdx.x * 256L + threadIdx.x;
  const long stride = (long)gridDim.x * 256L;
  for (; g < NG; g += stride) {
    const float* in;
    f16* out;
    long off;
    if (g < 3 * NGX) {
      const long w = g >> 20;
      off = (g - w * NGX) * 8;
      in = w == 0 ? x1 : (w == 1 ? x2 : x3);
      out = w == 0 ? o1 : (w == 1 ? o2 : o3);
    } else {
      const long gg = g - 3 * NGX;
      const long h = gg >> 17;
      off = (gg - h * NGW) * 8;
      in = h == 0 ? wq : (h == 1 ? wk : wv);
      out = h == 0 ? o4 : (h == 1 ? o5 : o6);
    }
    float4 u = *(const float4*)(in + off);
    float4 v = *(const float4*)(in + off + 4);
    h8 o;
    o[0] = (f16)u.x; o[1] = (f16)u.y; o[2] = (f16)u.z; o[3] = (f16)u.w;
    o[4] = (f16)v.x; o[5] = (f16)v.y; o[6] = (f16)v.z; o[7] = (f16)v.w;
    *(h8*)(out + off) = o;
  }
}

// ---------------- GEMM C = A * B^T, 4-slot ring, per-phase interleave, counted vmcnt ----------
// A [M,K], B [N,K] f16 row-major. BK=32 per tile. Parts = 128-row panels (1 load/thread each).
// Ring: tile t lives in slot t&3; tile t+3 staged (spread over tile t's phases); vmcnt(2P) per
// tile guarantees tile t+1 landed before tile t's last barrier. Never drains to 0 in-loop.
// MODE 0: f32 C[m*N+n] (+bz*sC). MODE 3: proj batched: bz<2 -> f16 C (+bz*sC); bz==2 -> V^T.
template <int BM, int BN, int WM, int WN, int MODE>
__global__ __launch_bounds__(512, 2) void gemmk(const f16* __restrict__ A,
                                                const f16* __restrict__ Bm,
                                                void* __restrict__ C,
                                                int N, int K,
                                                long sA, long sB, long sC,
                                                int gx, int gy) {
  constexpr int PA = BM / 128, PB = BN / 128, P = PA + PB;   // parts (loads) per tile
  constexpr int TGR = (BM + BN) * 4;                         // 16B granules per tile slot
  constexpr int MI = BM / WM / 16, NI = BN / WN / 16, H = MI / 4;
  extern __shared__ __align__(16) f16 smem[];                // 4 * TGR * 16 bytes

  // bijective XCD swizzle (grid % 8 == 0); by fastest within chunk
  const int cpx = gridDim.x >> 3;
  const int wgid = (blockIdx.x & 7) * cpx + (blockIdx.x >> 3);
  const int by = wgid % gy;
  const int bx = (wgid / gy) % gx;
  const int bz = wgid / (gy * gx);
  A += (long)bz * sA;
  Bm += (long)bz * sB;
  const int m0 = bx * BM, n0 = by * BN;

  const int tid = threadIdx.x;
  const int lane = tid & 63;
  const int w = tid >> 6;
  const int wm = w % WM, wn = w / WM;
  const int fr = lane & 15;
  const int kqx = lane >> 4;          // 0..3 (16B granule within 64B row)

  // stage mapping: part = 128 rows x 32 f16 = 512 granules; thread tid -> granule tid
  const int srow = tid >> 2;          // 0..127
  const int scol = (tid & 3) * 8;     // f16 col

  auto STAGEA = [&](int sb, int t) {
#pragma unroll
    for (int p = 0; p < PA; ++p)
      __builtin_amdgcn_global_load_lds(
          (gchar*)(A + (long)(m0 + p * 128 + srow) * K + t * 32 + scol),
          (lchar*)(smem + ((sb * TGR + p * 512 + w * 64) * 8)), 16, 0, 0);
  };
  auto STAGEB = [&](int sb, int t) {
#pragma unroll
    for (int p = 0; p < PB; ++p)
      __builtin_amdgcn_global_load_lds(
          (gchar*)(Bm + (long)(n0 + p * 128 + srow) * K + t * 32 + scol),
          (lchar*)(smem + ((sb * TGR + (PA + p) * 512 + w * 64) * 8)), 16, 0, 0);
  };

  f4 acc[MI][NI] = {};
  const int NT = K >> 5;

  // prologue: stage tiles 0,1,2 -> slots 0,1,2; wait tile0 (2P newest may fly)
  STAGEA(0, 0); STAGEB(0, 0);
  STAGEA(1, 1); STAGEB(1, 1);
  STAGEA(2, 2); STAGEB(2, 2);
  vmwait<2 * P>();
  __builtin_amdgcn_s_barrier();

  h8 bf[NI];
  for (int t = 0; t < NT; ++t) {
    const int tb = t & 3;
    const int ts = (t + 3 < NT) ? (t + 3) : (NT - 1);  // clamped: extra stages land in unread slots
    const int sb = (t + 3) & 3;
#pragma unroll
    for (int h = 0; h < H; ++h) {
      // ---- ds-load this phase's fragments (from slot tb) ----
      h8 af[4];
#pragma unroll
      for (int i = 0; i < 4; ++i) {
        const int row = wm * (BM / WM) + (h * 4 + i) * 16 + fr;
        af[i] = *(const h8*)(smem + ((tb * TGR + (row >> 7) * 512 + (row & 127) * 4 + kqx) * 8));
      }
      if (h == 0) {
#pragma unroll
        for (int j = 0; j < NI; ++j) {
          const int rowB = wn * (BN / WN) + j * 16 + fr;
          bf[j] = *(const h8*)(smem + ((tb * TGR + (PA + (rowB >> 7)) * 512 + (rowB & 127) * 4 + kqx) * 8));
        }
      }
      // ---- stage part(s) of tile t+3 (slot sb != tb) ----
      if constexpr (H == 2) {
        if (h == 0) STAGEA(sb, ts); else STAGEB(sb, ts);
      } else {
        STAGEA(sb, ts); STAGEB(sb, ts);
      }
      // ---- counted vmcnt once per tile: tile t+1's parts landed; t+2,t+3 stay in flight ----
      if (h == H - 1) vmwait<2 * P>();
      __builtin_amdgcn_s_barrier();
      asm volatile("s_waitcnt lgkmcnt(0)" ::: "memory");
      __builtin_amdgcn_sched_barrier(0);
      __builtin_amdgcn_s_setprio(1);
#pragma unroll
      for (int i = 0; i < 4; ++i)
#pragma unroll
        for (int j = 0; j < NI; ++j)
          acc[h * 4 + i][j] = __builtin_amdgcn_mfma_f32_16x16x32_f16(af[i], bf[j], acc[h * 4 + i][j], 0, 0, 0);
      __builtin_amdgcn_s_setprio(0);
      __builtin_amdgcn_s_barrier();
    }
  }
  vmwait<0>();  // drain DMA before exit

  // epilogue: C/D layout: col = lane&15, row = (lane>>4)*4 + reg
  const int fq = kqx * 4;
#pragma unroll
  for (int mi = 0; mi < MI; ++mi) {
#pragma unroll
    for (int ni = 0; ni < NI; ++ni) {
#pragma unroll
      for (int i = 0; i < 4; ++i) {
        const int row = m0 + wm * (BM / WM) + mi * 16 + fq + i;
        const int col = n0 + wn * (BN / WN) + ni * 16 + fr;
        const float val = acc[mi][ni][i];
        if constexpr (MODE == 0) {
          float* Cp = (float*)C + (long)bz * sC;
          Cp[(long)row * N + col] = val;
        } else {
          if (bz < 2) {
            f16* Cp = (f16*)C + (long)bz * sC;
            Cp[(long)row * N + col] = (f16)val;
          } else {
            f16* Cp = (f16*)C + 2 * sC;
            Cp[((long)(row >> 11) * N + col) * 2048 + (row & 2047)] = (f16)val;
          }
        }
      }
    }
  }
}

// ---------------- fused scale + mask + softmax, scores f32 -> P f16 ----------------
__global__ __launch_bounds__(256) void softmax_rows(const float* __restrict__ Sc,
                                                    const float* __restrict__ mask,
                                                    f16* __restrict__ P, float scale) {
  const long row = blockIdx.x;
  const float* s = Sc + row * (long)S_;
  const float* mk = mask + row * (long)S_;
  const int t = threadIdx.x;

  float4 a0 = *(const float4*)(s + t * 8);
  float4 a1 = *(const float4*)(s + t * 8 + 4);
  float4 b0 = *(const float4*)(mk + t * 8);
  float4 b1 = *(const float4*)(mk + t * 8 + 4);
  float v[8] = {a0.x * scale + b0.x, a0.y * scale + b0.y,
                a0.z * scale + b0.z, a0.w * scale + b0.w,
                a1.x * scale + b1.x, a1.y * scale + b1.y,
                a1.z * scale + b1.z, a1.w * scale + b1.w};

  float mx = v[0];
#pragma unroll
  for (int j = 1; j < 8; ++j) mx = fmaxf(mx, v[j]);
  for (int o = 32; o > 0; o >>= 1) mx = fmaxf(mx, __shfl_xor(mx, o));

  __shared__ float redm[4];
  __shared__ float reds[4];
  const int w = t >> 6;
  if ((t & 63) == 0) redm[w] = mx;
  __syncthreads();
  mx = fmaxf(fmaxf(redm[0], redm[1]), fmaxf(redm[2], redm[3]));

  float e[8];
  float sum = 0.f;
#pragma unroll
  for (int j = 0; j < 8; ++j) { e[j] = __expf(v[j] - mx); sum += e[j]; }
  for (int o = 32; o > 0; o >>= 1) sum += __shfl_xor(sum, o);
  if ((t & 63) == 0) reds[w] = sum;
  __syncthreads();
  sum = reds[0] + reds[1] + reds[2] + reds[3];
  const float inv = 1.0f / sum;

  h8 o;
#pragma unroll
  for (int j = 0; j < 8; ++j) o[j] = (f16)(e[j] * inv);
  *(h8*)(P + row * (long)S_ + t * 8) = o;
}

extern "C" void kernel_launch(void* const* d_in, const int* in_sizes, int n_in,
                              void* d_out, int out_size, void* d_ws, size_t ws_size,
                              hipStream_t stream) {
  const float* x1 = (const float*)d_in[0];
  const float* x2 = (const float*)d_in[1];
  const float* x3 = (const float*)d_in[2];
  const float* mask = (const float*)d_in[3];
  const float* Wq = (const float*)d_in[4];
  const float* Wk = (const float*)d_in[5];
  const float* Wv = (const float*)d_in[6];

  const long nx = (long)B_ * S_ * D_;
  const long nw = (long)H_ * D_;
  const long nqkv = (long)B_ * S_ * H_;
  const long nsc = (long)B_ * S_ * S_;

  char* ws = (char*)d_ws;
  f16* x1h = (f16*)ws; ws += nx * 2;
  f16* x2h = (f16*)ws; ws += nx * 2;   // contiguous after x1h
  f16* x3h = (f16*)ws; ws += nx * 2;   // contiguous
  f16* wqh = (f16*)ws; ws += nw * 2;
  f16* wkh = (f16*)ws; ws += nw * 2;   // contiguous after wqh
  f16* wvh = (f16*)ws; ws += nw * 2;
  f16* qh  = (f16*)ws; ws += nqkv * 2;
  f16* kh  = (f16*)ws; ws += nqkv * 2; // contiguous after qh
  f16* vth = (f16*)ws; ws += nqkv * 2; // [b][h][s], contiguous after kh
  float* sc = (float*)ws; ws += nsc * 4;
  f16* ph  = (f16*)ws; ws += nsc * 2;

  const int SM_SCORES = 4 * (256 + 256) * 4 * 16;  // 131072
  const int SM_RECT   = 4 * (256 + 128) * 4 * 16;  // 98304
  hipFuncSetAttribute((const void*)gemmk<256, 256, 2, 4, 0>,
                      hipFuncAttributeMaxDynamicSharedMemorySize, SM_SCORES);
  hipFuncSetAttribute((const void*)gemmk<256, 128, 4, 2, 3>,
                      hipFuncAttributeMaxDynamicSharedMemorySize, SM_RECT);
  hipFuncSetAttribute((const void*)gemmk<256, 128, 4, 2, 0>,
                      hipFuncAttributeMaxDynamicSharedMemorySize, SM_RECT);

  cast_all<<<2048, 256, 0, stream>>>(x1, x2, x3, Wq, Wk, Wv,
                                     x1h, x2h, x3h, wqh, wkh, wvh);

  const dim3 blk(512);
  // QKV projections, batched z=3 (z picks x/W/dest): 32 x 8 x 3 = 768 blocks (3 exact waves)
  gemmk<256, 128, 4, 2, 3><<<dim3(768), blk, SM_RECT, stream>>>(
      x1h, wqh, qh, 1024, 1024, nx, nw, nqkv, 32, 8);
  // scores[b] = Q[b] K[b]^T : 2048x2048x1024 x4, f32; 8 x 8 x 4 = 256 blocks (1 wave)
  gemmk<256, 256, 2, 4, 0><<<dim3(256), blk, SM_SCORES, stream>>>(
      qh, kh, sc, 2048, 1024, (long)S_ * H_, (long)S_ * H_, (long)S_ * S_, 8, 8);
  // P = softmax(scores * 1/sqrt(H) + mask)
  softmax_rows<<<B_ * S_, 256, 0, stream>>>(sc, mask, ph, 0.03125f);
  // out[b] = P[b] (V^T[b])^T : 2048x1024x2048 x4, f32 to d_out; 8 x 8 x 4 = 256 blocks
  gemmk<256, 128, 4, 2, 0><<<dim3(256), blk, SM_RECT, stream>>>(
      ph, vth, d_out, 1024, 2048, (long)S_ * S_, (long)S_ * H_, (long)S_ * H_, 8, 8);
}

// Round 6
// 250.085 us; speedup vs baseline: 1.1321x; 1.0151x over previous
//
#include <hip/hip_runtime.h>

typedef _Float16 f16;
typedef _Float16 h8 __attribute__((ext_vector_type(8)));
typedef float f4 __attribute__((ext_vector_type(4)));

typedef const __attribute__((address_space(1))) char gchar;
typedef __attribute__((address_space(3))) char lchar;

#define B_ 4
#define S_ 2048
#define D_ 1024
#define H_ 1024

template <int N>
__device__ __forceinline__ void vmwait() {
  if constexpr (N == 0) asm volatile("s_waitcnt vmcnt(0)" ::: "memory");
  else if constexpr (N == 4) asm volatile("s_waitcnt vmcnt(4)" ::: "memory");
}

// ---------------- fused fp32 -> fp16 cast of all six inputs ----------------
#define NGX (8388608L / 8)
#define NGW (1048576L / 8)

__global__ __launch_bounds__(256) void cast_all(
    const float* __restrict__ x1, const float* __restrict__ x2, const float* __restrict__ x3,
    const float* __restrict__ wq, const float* __restrict__ wk, const float* __restrict__ wv,
    f16* __restrict__ o1, f16* __restrict__ o2, f16* __restrict__ o3,
    f16* __restrict__ o4, f16* __restrict__ o5, f16* __restrict__ o6) {
  const long NG = 3 * NGX + 3 * NGW;
  long g = blockIdx.x * 256L + threadIdx.x;
  const long stride = (long)gridDim.x * 256L;
  for (; g < NG; g += stride) {
    const float* in;
    f16* out;
    long off;
    if (g < 3 * NGX) {
      const long w = g >> 20;
      off = (g - w * NGX) * 8;
      in = w == 0 ? x1 : (w == 1 ? x2 : x3);
      out = w == 0 ? o1 : (w == 1 ? o2 : o3);
    } else {
      const long gg = g - 3 * NGX;
      const long h = gg >> 17;
      off = (gg - h * NGW) * 8;
      in = h == 0 ? wq : (h == 1 ? wk : wv);
      out = h == 0 ? o4 : (h == 1 ? o5 : o6);
    }
    float4 u = *(const float4*)(in + off);
    float4 v = *(const float4*)(in + off + 4);
    h8 o;
    o[0] = (f16)u.x; o[1] = (f16)u.y; o[2] = (f16)u.z; o[3] = (f16)u.w;
    o[4] = (f16)v.x; o[5] = (f16)v.y; o[6] = (f16)v.z; o[7] = (f16)v.w;
    *(h8*)(out + off) = o;
  }
}

// ---------- GEMM C = A * B^T : 128x128/BK32, 3-slot ring, counted vmcnt(4), T2 swizzle ----------
// A [M,K], B [N,K] f16 row-major. 256 threads = 2x2 waves, 16 MFMA/wave/K-step.
// Ring ledger: tile t in slot t%3; iter t stages tile t+2 into slot (t+2)%3 (= slot of t-1,
// fully read before prev barrier). vmwait(4) retires tile t+1's 4 loads; tile t+2's stay
// in flight across the barrier. LDS slot granule (row, s) holds global k-slot s^((row>>1)&3)
// (8-way bank conflict -> 2-way); staged by pre-swizzling the per-lane GLOBAL source.
// MODE 0: f32 C[m*N+n] (+bz*sC).
// MODE 3: proj batched: bz<2 -> f16 C[m*N+n] (+bz*sC); bz==2 -> V^T C[((m>>11)*N+col)*2048+(m&2047)].
template <int MODE>
__global__ __launch_bounds__(256, 3) void gemm128(const f16* __restrict__ A,
                                                  const f16* __restrict__ Bm,
                                                  void* __restrict__ C,
                                                  int N, int K,
                                                  long sA, long sB, long sC,
                                                  int gx, int gy) {
  __shared__ __align__(16) f16 smem[3 * 8192];  // 3 slots x (A 4096 + B 4096) f16 = 48 KiB

  // bijective XCD swizzle (grid % 8 == 0); by fastest (neighbor blocks share A panel)
  const int cpx = gridDim.x >> 3;
  const int wgid = (blockIdx.x & 7) * cpx + (blockIdx.x >> 3);
  const int by = wgid % gy;
  const int bx = (wgid / gy) % gx;
  const int bz = wgid / (gy * gx);
  A += (long)bz * sA;
  Bm += (long)bz * sB;
  const int m0 = bx * 128, n0 = by * 128;

  const int tid = threadIdx.x;
  const int lane = tid & 63;
  const int w = tid >> 6;
  const int wr = w >> 1, wc = w & 1;
  const int fr = lane & 15;
  const int g = lane >> 4;  // k-granule 0..3 (8 f16 each)

  // staging: thread -> (row0 = tid>>2, s = tid&3); 2 chunks of 64 rows; LDS dest linear
  // (granule c*256 + tid), global source col pre-swizzled so read-side XOR recovers k-order.
  const int r0 = tid >> 2;
  const int s = tid & 3;

  auto STAGE = [&](int sl, int t) {
    const long k0 = (long)t * 32;
#pragma unroll
    for (int c = 0; c < 2; ++c) {
      const int row = c * 64 + r0;
      const int scol = (s ^ ((row >> 1) & 3)) * 8;
      __builtin_amdgcn_global_load_lds(
          (gchar*)(A + (long)(m0 + row) * K + k0 + scol),
          (lchar*)(smem + sl * 8192 + (c * 256 + w * 64) * 8), 16, 0, 0);
      __builtin_amdgcn_global_load_lds(
          (gchar*)(Bm + (long)(n0 + row) * K + k0 + scol),
          (lchar*)(smem + sl * 8192 + 4096 + (c * 256 + w * 64) * 8), 16, 0, 0);
    }
  };

  // swizzled fragment read: global k-granule g of row r lives at granule r*4 + (g^((r>>1)&3))
  auto RD = [&](int sl, int mat, int r) -> h8 {
    return *(const h8*)(smem + sl * 8192 + mat * 4096 + (r * 4 + (g ^ ((r >> 1) & 3))) * 8);
  };

  f4 acc[4][4] = {};
  const int NT = K >> 5;

  STAGE(0, 0);
  STAGE(1, 1);
  vmwait<4>();                     // tile 0 landed; tile 1 in flight
  __builtin_amdgcn_s_barrier();

  int sl = 0;
  for (int t = 0; t < NT; ++t) {
    h8 af[4], bf[4];
#pragma unroll
    for (int i = 0; i < 4; ++i) {
      af[i] = RD(sl, 0, wr * 64 + i * 16 + fr);
      bf[i] = RD(sl, 1, wc * 64 + i * 16 + fr);
    }
    const int ts = (t + 2 < NT) ? t + 2 : NT - 1;  // tail dups land in never-read slots
    int ss = sl + 2; if (ss >= 3) ss -= 3;
    STAGE(ss, ts);
    vmwait<4>();                   // tile t+1's 4 loads retired; t+2's stay in flight
    asm volatile("s_waitcnt lgkmcnt(0)" ::: "memory");
    __builtin_amdgcn_sched_barrier(0);
    __builtin_amdgcn_s_setprio(1);
#pragma unroll
    for (int mi = 0; mi < 4; ++mi)
#pragma unroll
      for (int ni = 0; ni < 4; ++ni)
        acc[mi][ni] = __builtin_amdgcn_mfma_f32_16x16x32_f16(af[mi], bf[ni], acc[mi][ni], 0, 0, 0);
    __builtin_amdgcn_s_setprio(0);
    __builtin_amdgcn_s_barrier();  // all waves done reading slot sl; next iter may stage into it
    sl = (sl + 1 == 3) ? 0 : sl + 1;
  }
  vmwait<0>();  // retire this wave's in-flight DMA before exit

  // epilogue: C/D layout (measured): col = lane&15, row = (lane>>4)*4 + reg
  const int fq = g * 4;
#pragma unroll
  for (int mi = 0; mi < 4; ++mi) {
#pragma unroll
    for (int ni = 0; ni < 4; ++ni) {
#pragma unroll
      for (int i = 0; i < 4; ++i) {
        const int row = m0 + wr * 64 + mi * 16 + fq + i;
        const int col = n0 + wc * 64 + ni * 16 + fr;
        const float val = acc[mi][ni][i];
        if constexpr (MODE == 0) {
          float* Cp = (float*)C + (long)bz * sC;
          Cp[(long)row * N + col] = val;
        } else {
          if (bz < 2) {
            f16* Cp = (f16*)C + (long)bz * sC;
            Cp[(long)row * N + col] = (f16)val;
          } else {
            f16* Cp = (f16*)C + 2 * sC;
            Cp[((long)(row >> 11) * N + col) * 2048 + (row & 2047)] = (f16)val;
          }
        }
      }
    }
  }
}

// ---------------- fused scale + mask + softmax, scores f32 -> P f16 ----------------
__global__ __launch_bounds__(256) void softmax_rows(const float* __restrict__ Sc,
                                                    const float* __restrict__ mask,
                                                    f16* __restrict__ P, float scale) {
  const long row = blockIdx.x;
  const float* s = Sc + row * (long)S_;
  const float* mk = mask + row * (long)S_;
  const int t = threadIdx.x;

  float4 a0 = *(const float4*)(s + t * 8);
  float4 a1 = *(const float4*)(s + t * 8 + 4);
  float4 b0 = *(const float4*)(mk + t * 8);
  float4 b1 = *(const float4*)(mk + t * 8 + 4);
  float v[8] = {a0.x * scale + b0.x, a0.y * scale + b0.y,
                a0.z * scale + b0.z, a0.w * scale + b0.w,
                a1.x * scale + b1.x, a1.y * scale + b1.y,
                a1.z * scale + b1.z, a1.w * scale + b1.w};

  float mx = v[0];
#pragma unroll
  for (int j = 1; j < 8; ++j) mx = fmaxf(mx, v[j]);
  for (int o = 32; o > 0; o >>= 1) mx = fmaxf(mx, __shfl_xor(mx, o));

  __shared__ float redm[4];
  __shared__ float reds[4];
  const int w = t >> 6;
  if ((t & 63) == 0) redm[w] = mx;
  __syncthreads();
  mx = fmaxf(fmaxf(redm[0], redm[1]), fmaxf(redm[2], redm[3]));

  float e[8];
  float sum = 0.f;
#pragma unroll
  for (int j = 0; j < 8; ++j) { e[j] = __expf(v[j] - mx); sum += e[j]; }
  for (int o = 32; o > 0; o >>= 1) sum += __shfl_xor(sum, o);
  if ((t & 63) == 0) reds[w] = sum;
  __syncthreads();
  sum = reds[0] + reds[1] + reds[2] + reds[3];
  const float inv = 1.0f / sum;

  h8 o;
#pragma unroll
  for (int j = 0; j < 8; ++j) o[j] = (f16)(e[j] * inv);
  *(h8*)(P + row * (long)S_ + t * 8) = o;
}

extern "C" void kernel_launch(void* const* d_in, const int* in_sizes, int n_in,
                              void* d_out, int out_size, void* d_ws, size_t ws_size,
                              hipStream_t stream) {
  const float* x1 = (const float*)d_in[0];
  const float* x2 = (const float*)d_in[1];
  const float* x3 = (const float*)d_in[2];
  const float* mask = (const float*)d_in[3];
  const float* Wq = (const float*)d_in[4];
  const float* Wk = (const float*)d_in[5];
  const float* Wv = (const float*)d_in[6];

  const long nx = (long)B_ * S_ * D_;
  const long nw = (long)H_ * D_;
  const long nqkv = (long)B_ * S_ * H_;
  const long nsc = (long)B_ * S_ * S_;

  char* ws = (char*)d_ws;
  f16* x1h = (f16*)ws; ws += nx * 2;
  f16* x2h = (f16*)ws; ws += nx * 2;   // contiguous after x1h
  f16* x3h = (f16*)ws; ws += nx * 2;   // contiguous
  f16* wqh = (f16*)ws; ws += nw * 2;
  f16* wkh = (f16*)ws; ws += nw * 2;   // contiguous after wqh
  f16* wvh = (f16*)ws; ws += nw * 2;
  f16* qh  = (f16*)ws; ws += nqkv * 2;
  f16* kh  = (f16*)ws; ws += nqkv * 2; // contiguous after qh
  f16* vth = (f16*)ws; ws += nqkv * 2; // [b][h][s], contiguous after kh
  float* sc = (float*)ws; ws += nsc * 4;
  f16* ph  = (f16*)ws; ws += nsc * 2;

  cast_all<<<2048, 256, 0, stream>>>(x1, x2, x3, Wq, Wk, Wv,
                                     x1h, x2h, x3h, wqh, wkh, wvh);

  const dim3 blk(256);
  // QKV projections batched z=3: 64 x 8 x 3 = 1536 blocks (2 exact rounds at 3 blocks/CU)
  gemm128<3><<<dim3(1536), blk, 0, stream>>>(x1h, wqh, qh, 1024, 1024,
                                             nx, nw, nqkv, 64, 8);
  // scores[b] = Q[b] K[b]^T : 2048x2048x1024 x4, f32; 16 x 16 x 4 = 1024 blocks
  gemm128<0><<<dim3(1024), blk, 0, stream>>>(qh, kh, sc, 2048, 1024,
                                             (long)S_ * H_, (long)S_ * H_, (long)S_ * S_, 16, 16);
  // P = softmax(scores * 1/sqrt(H) + mask)
  softmax_rows<<<B_ * S_, 256, 0, stream>>>(sc, mask, ph, 0.03125f);
  // out[b] = P[b] (V^T[b])^T : 2048x1024x2048 x4, f32 to d_out; 16 x 8 x 4 = 512 blocks
  gemm128<0><<<dim3(512), blk, 0, stream>>>(ph, vth, d_out, 1024, 2048,
                                            (long)S_ * S_, (long)S_ * H_, (long)S_ * H_, 16, 8);
}